// Round 3
// baseline (3206.004 us; speedup 1.0000x reference)
//
#include <hip/hip_runtime.h>

#define N_NODES 100000
#define IN_DIM 128
#define HID 64
#define OUT_DIM 5
#define N_EDGES 3200000

#define BSHIFT 7
#define BROWS 128  // nodes per bucket
#define NBUCK ((N_NODES + BROWS - 1) / BROWS)  // 782
#define FILL_CHUNK 16384
#define NBLK_FILL ((N_EDGES + FILL_CHUNK - 1) / FILL_CHUNK)  // 196

// ---- bucket histogram: bcount[dst>>7] += 1, LDS-aggregated ----
__global__ __launch_bounds__(256) void bcount_k(const int* __restrict__ dst,
                                                int* __restrict__ bcount, int E) {
  __shared__ int h[NBUCK];
  const int t = threadIdx.x;
  for (int i = t; i < NBUCK; i += 256) h[i] = 0;
  __syncthreads();
  int i = blockIdx.x * blockDim.x + t;
  const int stride = gridDim.x * blockDim.x;
  for (int e = i; e < E; e += stride) atomicAdd(&h[dst[e] >> BSHIFT], 1);
  __syncthreads();
  for (int b = t; b < NBUCK; b += 256) {
    const int v = h[b];
    if (v) atomicAdd(&bcount[b], v);
  }
}

// ---- exclusive scan of 782 bucket counts (single block) ----
__global__ __launch_bounds__(256) void bscan_k(const int* __restrict__ bcount,
                                               int* __restrict__ boff) {
  __shared__ int tsum[256];
  const int t = threadIdx.x;
  int v[4];
  int s = 0;
#pragma unroll
  for (int j = 0; j < 4; ++j) {
    const int idx = t * 4 + j;
    v[j] = (idx < NBUCK) ? bcount[idx] : 0;
    s += v[j];
  }
  tsum[t] = s;
  __syncthreads();
  for (int off = 1; off < 256; off <<= 1) {
    int x = (t >= off) ? tsum[t - off] : 0;
    __syncthreads();
    tsum[t] += x;
    __syncthreads();
  }
  int pre = tsum[t] - s;
#pragma unroll
  for (int j = 0; j < 4; ++j) {
    const int idx = t * 4 + j;
    if (idx < NBUCK) boff[idx] = pre;
    pre += v[j];
  }
  if (t == 0) boff[NBUCK] = N_EDGES;
}

// ---- two-level bucket fill: per-block LDS histogram + range reservation ----
// bedge[pos] = (src << 7) | (dst & 127); src < 2^17 so value fits 24 bits.
__global__ __launch_bounds__(256) void fillB_k(const int* __restrict__ src,
                                               const int* __restrict__ dst,
                                               const int* __restrict__ boff,
                                               int* __restrict__ bcursor,
                                               int* __restrict__ bedge) {
  __shared__ int hist[NBUCK];
  __shared__ int base[NBUCK];
  __shared__ int cur[NBUCK];
  const int t = threadIdx.x;
  const int e0 = blockIdx.x * FILL_CHUNK;
  const int e1 = min(e0 + FILL_CHUNK, N_EDGES);
  for (int i = t; i < NBUCK; i += 256) {
    hist[i] = 0;
    cur[i] = 0;
  }
  __syncthreads();
  for (int e = e0 + t; e < e1; e += 256) atomicAdd(&hist[dst[e] >> BSHIFT], 1);
  __syncthreads();
  for (int b = t; b < NBUCK; b += 256) {
    const int v = hist[b];
    base[b] = v ? atomicAdd(&bcursor[b], v) : 0;
  }
  __syncthreads();
  for (int e = e0 + t; e < e1; e += 256) {
    const int d = dst[e];
    const int b = d >> BSHIFT;
    const int pos = boff[b] + base[b] + atomicAdd(&cur[b], 1);
    bedge[pos] = (src[e] << BSHIFT) | (d & (BROWS - 1));
  }
}

// ---- fused dual GEMM: Y = X @ Wl^T, Z = X @ Wr^T  (Wl,Wr are [64][K] row-major) ----
template <int K>
__global__ __launch_bounds__(256) void gemm_dual(const float* __restrict__ X,
                                                 const float* __restrict__ Wl,
                                                 const float* __restrict__ Wr,
                                                 float* __restrict__ Y,
                                                 float* __restrict__ Z, int n) {
  __shared__ float xT[K * 65];
  __shared__ float tbuf[64 * 65];
  const int t = threadIdx.x;
  const int lane = t & 63;
  const int wv = __builtin_amdgcn_readfirstlane(t >> 6);
  const int colBase = wv * 16;
  const int rowBase = blockIdx.x * 64;

  for (int i = t; i < 64 * K; i += 256) {
    const int r = i / K, k = i - r * K;
    const int row = rowBase + r;
    xT[k * 65 + r] = (row < n) ? X[(size_t)row * K + k] : 0.0f;
  }
  __syncthreads();

  float accY[16], accZ[16];
#pragma unroll
  for (int j = 0; j < 16; ++j) { accY[j] = 0.0f; accZ[j] = 0.0f; }

  for (int k = 0; k < K; ++k) {
    const float xv = xT[k * 65 + lane];
#pragma unroll
    for (int j = 0; j < 16; ++j) {
      accY[j] = fmaf(xv, Wl[(colBase + j) * K + k], accY[j]);
      accZ[j] = fmaf(xv, Wr[(colBase + j) * K + k], accZ[j]);
    }
  }

#pragma unroll
  for (int j = 0; j < 16; ++j) tbuf[lane * 65 + colBase + j] = accY[j];
  __syncthreads();
  for (int i = t; i < 64 * 64; i += 256) {
    const int r = i >> 6, c = i & 63;
    if (rowBase + r < n) Y[(size_t)(rowBase + r) * 64 + c] = tbuf[r * 65 + c];
  }
  __syncthreads();
#pragma unroll
  for (int j = 0; j < 16; ++j) tbuf[lane * 65 + colBase + j] = accZ[j];
  __syncthreads();
  for (int i = t; i < 64 * 64; i += 256) {
    const int r = i >> 6, c = i & 63;
    if (rowBase + r < n) Z[(size_t)(rowBase + r) * 64 + c] = tbuf[r * 65 + c];
  }
}

// ---- bucketed gather: block per bucket, LDS accumulate, fused epilogue ----
template <bool FINAL>
__global__ __launch_bounds__(256) void gatherB_k(
    const int* __restrict__ boff, const int* __restrict__ bedge,
    const float* __restrict__ Y, const float* __restrict__ Z,
    const float* __restrict__ bias, const float* __restrict__ Wh,
    const float* __restrict__ bh, float* __restrict__ H,
    float* __restrict__ logits) {
  __shared__ float acc[BROWS * 65];  // [row][0..63]=channels, [64]=count
  const int t = threadIdx.x;
  const int lane = t & 63;
  const int wv = t >> 6;
  const int b = blockIdx.x;
  for (int i = t; i < BROWS * 65; i += 256) acc[i] = 0.0f;
  __syncthreads();

  const int e0 = boff[b];
  const int e1 = boff[b + 1];
  for (int eb = e0 + wv * 64; eb < e1; eb += 256) {
    const int m = min(64, e1 - eb);
    const int p = (lane < m) ? bedge[eb + lane] : 0;
    int j = 0;
    for (; j + 3 < m; j += 4) {
      const int p0 = __shfl(p, j);
      const int p1 = __shfl(p, j + 1);
      const int p2 = __shfl(p, j + 2);
      const int p3 = __shfl(p, j + 3);
      const float y0 = Y[(size_t)(p0 >> BSHIFT) * 64 + lane];
      const float y1 = Y[(size_t)(p1 >> BSHIFT) * 64 + lane];
      const float y2 = Y[(size_t)(p2 >> BSHIFT) * 64 + lane];
      const float y3 = Y[(size_t)(p3 >> BSHIFT) * 64 + lane];
      atomicAdd(&acc[(p0 & (BROWS - 1)) * 65 + lane], y0);
      atomicAdd(&acc[(p1 & (BROWS - 1)) * 65 + lane], y1);
      atomicAdd(&acc[(p2 & (BROWS - 1)) * 65 + lane], y2);
      atomicAdd(&acc[(p3 & (BROWS - 1)) * 65 + lane], y3);
      if (lane == 0) {
        atomicAdd(&acc[(p0 & (BROWS - 1)) * 65 + 64], 1.0f);
        atomicAdd(&acc[(p1 & (BROWS - 1)) * 65 + 64], 1.0f);
        atomicAdd(&acc[(p2 & (BROWS - 1)) * 65 + 64], 1.0f);
        atomicAdd(&acc[(p3 & (BROWS - 1)) * 65 + 64], 1.0f);
      }
    }
    for (; j < m; ++j) {
      const int p0 = __shfl(p, j);
      const float y0 = Y[(size_t)(p0 >> BSHIFT) * 64 + lane];
      atomicAdd(&acc[(p0 & (BROWS - 1)) * 65 + lane], y0);
      if (lane == 0) atomicAdd(&acc[(p0 & (BROWS - 1)) * 65 + 64], 1.0f);
    }
  }
  __syncthreads();

  // epilogue: h = relu(acc/max(cnt,1) + bias + Z); FINAL adds 5-logit head
  const float bl = bias[lane];
  float wh0 = 0.f, wh1 = 0.f, wh2 = 0.f, wh3 = 0.f, wh4 = 0.f;
  if (FINAL) {
    wh0 = Wh[0 * 64 + lane];
    wh1 = Wh[1 * 64 + lane];
    wh2 = Wh[2 * 64 + lane];
    wh3 = Wh[3 * 64 + lane];
    wh4 = Wh[4 * 64 + lane];
  }
  for (int r = wv; r < BROWS; r += 4) {
    const int node = b * BROWS + r;
    if (node >= N_NODES) break;
    const float cnt = acc[r * 65 + 64];
    const float inv = 1.0f / fmaxf(cnt, 1.0f);
    const float h =
        fmaxf(fmaf(acc[r * 65 + lane], inv, bl + Z[(size_t)node * 64 + lane]), 0.0f);
    H[(size_t)node * 64 + lane] = h;
    if (FINAL) {
      float p0 = h * wh0, p1 = h * wh1, p2 = h * wh2, p3 = h * wh3, p4 = h * wh4;
      for (int o = 32; o > 0; o >>= 1) {
        p0 += __shfl_xor(p0, o);
        p1 += __shfl_xor(p1, o);
        p2 += __shfl_xor(p2, o);
        p3 += __shfl_xor(p3, o);
        p4 += __shfl_xor(p4, o);
      }
      if (lane == 0) {
        logits[(size_t)node * 5 + 0] = p0 + bh[0];
        logits[(size_t)node * 5 + 1] = p1 + bh[1];
        logits[(size_t)node * 5 + 2] = p2 + bh[2];
        logits[(size_t)node * 5 + 3] = p3 + bh[3];
        logits[(size_t)node * 5 + 4] = p4 + bh[4];
      }
    }
  }
}

extern "C" void kernel_launch(void* const* d_in, const int* in_sizes, int n_in,
                              void* d_out, int out_size, void* d_ws, size_t ws_size,
                              hipStream_t stream) {
  const float* x = (const float*)d_in[0];
  const int* edge = (const int*)d_in[1];
  const float* W1l = (const float*)d_in[2];
  const float* b1l = (const float*)d_in[3];
  const float* W1r = (const float*)d_in[4];
  const float* W2l = (const float*)d_in[5];
  const float* b2l = (const float*)d_in[6];
  const float* W2r = (const float*)d_in[7];
  const float* Wh = (const float*)d_in[8];
  const float* bh = (const float*)d_in[9];
  const int* src = edge;
  const int* dst = edge + N_EDGES;

  float* out = (float*)d_out;
  float* logits = out;                            // [N,5]
  float* hout = out + (size_t)N_NODES * OUT_DIM;  // [N,64]

  const size_t N64 = (size_t)N_NODES * 64;
  float* y = (float*)d_ws;        // [N,64]
  float* z = y + N64;             // [N,64]
  float* h1 = z + N64;            // [N,64]
  int* bcount = (int*)(h1 + N64);   // [NBUCK]
  int* boff = bcount + NBUCK;       // [NBUCK+1]
  int* bcursor = boff + NBUCK + 1;  // [NBUCK]
  int* bedge = bcursor + NBUCK;     // [E]

  // ---- bucket build (once; shared by both layers) ----
  hipMemsetAsync(bcount, 0, NBUCK * sizeof(int), stream);
  hipMemsetAsync(bcursor, 0, NBUCK * sizeof(int), stream);
  bcount_k<<<512, 256, 0, stream>>>(dst, bcount, N_EDGES);
  bscan_k<<<1, 256, 0, stream>>>(bcount, boff);
  fillB_k<<<NBLK_FILL, 256, 0, stream>>>(src, dst, boff, bcursor, bedge);

  const int gblocks = (N_NODES + 63) / 64;

  // ---- layer 1 ----
  gemm_dual<IN_DIM><<<gblocks, 256, 0, stream>>>(x, W1l, W1r, y, z, N_NODES);
  gatherB_k<false><<<NBUCK, 256, 0, stream>>>(boff, bedge, y, z, b1l, nullptr,
                                              nullptr, h1, nullptr);

  // ---- layer 2 + head ----
  gemm_dual<HID><<<gblocks, 256, 0, stream>>>(h1, W2l, W2r, y, z, N_NODES);
  gatherB_k<true><<<NBUCK, 256, 0, stream>>>(boff, bedge, y, z, b2l, Wh, bh, hout,
                                             logits);
}

// Round 4
// 571.224 us; speedup vs baseline: 5.6125x; 5.6125x over previous
//
#include <hip/hip_runtime.h>

#define N_NODES 100000
#define IN_DIM 128
#define HID 64
#define OUT_DIM 5
#define N_EDGES 3200000

#define BSHIFT 7
#define BROWS 128  // nodes per bucket
#define NBUCK ((N_NODES + BROWS - 1) / BROWS)  // 782
#define FILL_CHUNK 16384
#define NBLK_FILL ((N_EDGES + FILL_CHUNK - 1) / FILL_CHUNK)  // 196

// ---- bucket histogram: bcount[dst>>7] += 1, LDS-aggregated ----
__global__ __launch_bounds__(256) void bcount_k(const int* __restrict__ dst,
                                                int* __restrict__ bcount, int E) {
  __shared__ int h[NBUCK];
  const int t = threadIdx.x;
  for (int i = t; i < NBUCK; i += 256) h[i] = 0;
  __syncthreads();
  int i = blockIdx.x * blockDim.x + t;
  const int stride = gridDim.x * blockDim.x;
  for (int e = i; e < E; e += stride) atomicAdd(&h[dst[e] >> BSHIFT], 1);
  __syncthreads();
  for (int b = t; b < NBUCK; b += 256) {
    const int v = h[b];
    if (v) atomicAdd(&bcount[b], v);
  }
}

// ---- exclusive scan of 782 bucket counts (single block); also noff sentinel ----
__global__ __launch_bounds__(256) void bscan_k(const int* __restrict__ bcount,
                                               int* __restrict__ boff,
                                               int* __restrict__ noff) {
  __shared__ int tsum[256];
  const int t = threadIdx.x;
  int v[4];
  int s = 0;
#pragma unroll
  for (int j = 0; j < 4; ++j) {
    const int idx = t * 4 + j;
    v[j] = (idx < NBUCK) ? bcount[idx] : 0;
    s += v[j];
  }
  tsum[t] = s;
  __syncthreads();
  for (int off = 1; off < 256; off <<= 1) {
    int x = (t >= off) ? tsum[t - off] : 0;
    __syncthreads();
    tsum[t] += x;
    __syncthreads();
  }
  int pre = tsum[t] - s;
#pragma unroll
  for (int j = 0; j < 4; ++j) {
    const int idx = t * 4 + j;
    if (idx < NBUCK) boff[idx] = pre;
    pre += v[j];
  }
  if (t == 0) {
    boff[NBUCK] = N_EDGES;
    noff[N_NODES] = N_EDGES;
  }
}

// ---- two-level bucket fill: per-block LDS histogram + range reservation ----
// bedge[pos] = (src << 7) | (dst & 127); src < 2^17 so value fits in int.
__global__ __launch_bounds__(256) void fillB_k(const int* __restrict__ src,
                                               const int* __restrict__ dst,
                                               const int* __restrict__ boff,
                                               int* __restrict__ bcursor,
                                               int* __restrict__ bedge) {
  __shared__ int hist[NBUCK];
  __shared__ int base[NBUCK];
  __shared__ int cur[NBUCK];
  const int t = threadIdx.x;
  const int e0 = blockIdx.x * FILL_CHUNK;
  const int e1 = min(e0 + FILL_CHUNK, N_EDGES);
  for (int i = t; i < NBUCK; i += 256) {
    hist[i] = 0;
    cur[i] = 0;
  }
  __syncthreads();
  for (int e = e0 + t; e < e1; e += 256) atomicAdd(&hist[dst[e] >> BSHIFT], 1);
  __syncthreads();
  for (int b = t; b < NBUCK; b += 256) {
    const int v = hist[b];
    base[b] = v ? atomicAdd(&bcursor[b], v) : 0;
  }
  __syncthreads();
  for (int e = e0 + t; e < e1; e += 256) {
    const int d = dst[e];
    const int b = d >> BSHIFT;
    const int pos = boff[b] + base[b] + atomicAdd(&cur[b], 1);
    bedge[pos] = (src[e] << BSHIFT) | (d & (BROWS - 1));
  }
}

// ---- bucket -> full CSR: block per bucket, LDS counting sort ----
// csr[noff[node] .. noff[node+1]) = src list for node. Writes stay inside the
// bucket's contiguous ~16KB range -> L2-absorbed, ~1x write amp.
__global__ __launch_bounds__(256) void csrfill_k(const int* __restrict__ boff,
                                                 const int* __restrict__ bedge,
                                                 int* __restrict__ csr,
                                                 int* __restrict__ noff) {
  __shared__ int hist[BROWS];
  __shared__ int sc[BROWS];
  __shared__ int cur[BROWS];
  const int t = threadIdx.x;
  const int b = blockIdx.x;
  const int e0 = boff[b];
  const int e1 = boff[b + 1];
  if (t < BROWS) {
    hist[t] = 0;
    cur[t] = 0;
  }
  __syncthreads();
  for (int e = e0 + t; e < e1; e += 256) atomicAdd(&hist[bedge[e] & (BROWS - 1)], 1);
  __syncthreads();
  if (t < BROWS) sc[t] = hist[t];
  __syncthreads();
  // Hillis-Steele inclusive scan over 128 entries
  for (int off = 1; off < BROWS; off <<= 1) {
    int x = (t >= off && t < BROWS) ? sc[t - off] : 0;
    __syncthreads();
    if (t < BROWS) sc[t] += x;
    __syncthreads();
  }
  if (t < BROWS) {
    const int node = b * BROWS + t;
    if (node < N_NODES) noff[node] = e0 + sc[t] - hist[t];  // exclusive
    sc[t] -= hist[t];
  }
  __syncthreads();
  for (int e = e0 + t; e < e1; e += 256) {
    const int p = bedge[e];
    const int d = p & (BROWS - 1);
    const int pos = e0 + sc[d] + atomicAdd(&cur[d], 1);
    csr[pos] = p >> BSHIFT;
  }
}

// ---- fused dual GEMM: Y = X @ Wl^T, Z = X @ Wr^T  (Wl,Wr are [64][K] row-major) ----
template <int K>
__global__ __launch_bounds__(256) void gemm_dual(const float* __restrict__ X,
                                                 const float* __restrict__ Wl,
                                                 const float* __restrict__ Wr,
                                                 float* __restrict__ Y,
                                                 float* __restrict__ Z, int n) {
  __shared__ float xT[K * 65];
  __shared__ float tbuf[64 * 65];
  const int t = threadIdx.x;
  const int lane = t & 63;
  const int wv = __builtin_amdgcn_readfirstlane(t >> 6);
  const int colBase = wv * 16;
  const int rowBase = blockIdx.x * 64;

  for (int i = t; i < 64 * K; i += 256) {
    const int r = i / K, k = i - r * K;
    const int row = rowBase + r;
    xT[k * 65 + r] = (row < n) ? X[(size_t)row * K + k] : 0.0f;
  }
  __syncthreads();

  float accY[16], accZ[16];
#pragma unroll
  for (int j = 0; j < 16; ++j) { accY[j] = 0.0f; accZ[j] = 0.0f; }

  for (int k = 0; k < K; ++k) {
    const float xv = xT[k * 65 + lane];
#pragma unroll
    for (int j = 0; j < 16; ++j) {
      accY[j] = fmaf(xv, Wl[(colBase + j) * K + k], accY[j]);
      accZ[j] = fmaf(xv, Wr[(colBase + j) * K + k], accZ[j]);
    }
  }

#pragma unroll
  for (int j = 0; j < 16; ++j) tbuf[lane * 65 + colBase + j] = accY[j];
  __syncthreads();
  for (int i = t; i < 64 * 64; i += 256) {
    const int r = i >> 6, c = i & 63;
    if (rowBase + r < n) Y[(size_t)(rowBase + r) * 64 + c] = tbuf[r * 65 + c];
  }
  __syncthreads();
#pragma unroll
  for (int j = 0; j < 16; ++j) tbuf[lane * 65 + colBase + j] = accZ[j];
  __syncthreads();
  for (int i = t; i < 64 * 64; i += 256) {
    const int r = i >> 6, c = i & 63;
    if (rowBase + r < n) Z[(size_t)(rowBase + r) * 64 + c] = tbuf[r * 65 + c];
  }
}

// ---- gather-reduce per node + fused epilogue ----
// wave per dst row; lane = channel; 4 independent accumulators for MLP.
template <bool FINAL>
__global__ __launch_bounds__(256) void gather_k(
    const int* __restrict__ noff, const int* __restrict__ csr,
    const float* __restrict__ Y, const float* __restrict__ Z,
    const float* __restrict__ bias, const float* __restrict__ Wh,
    const float* __restrict__ bh, float* __restrict__ H,
    float* __restrict__ logits, int n) {
  const int lane = threadIdx.x & 63;
  const int wid = (blockIdx.x * blockDim.x + threadIdx.x) >> 6;
  const int nw = (gridDim.x * blockDim.x) >> 6;
  float wh0 = 0.f, wh1 = 0.f, wh2 = 0.f, wh3 = 0.f, wh4 = 0.f;
  if (FINAL) {
    wh0 = Wh[0 * 64 + lane];
    wh1 = Wh[1 * 64 + lane];
    wh2 = Wh[2 * 64 + lane];
    wh3 = Wh[3 * 64 + lane];
    wh4 = Wh[4 * 64 + lane];
  }
  const float bl = bias[lane];

  for (int row = wid; row < n; row += nw) {
    const int e0 = noff[row];
    const int e1 = noff[row + 1];
    const float zv = Z[(size_t)row * 64 + lane];
    float acc0 = 0.0f, acc1 = 0.0f, acc2 = 0.0f, acc3 = 0.0f;
    for (int eb = e0; eb < e1; eb += 64) {
      const int m = min(64, e1 - eb);
      const int sidx = (eb + lane < e1) ? csr[eb + lane] : 0;
      int j = 0;
      for (; j + 3 < m; j += 4) {
        const int s0 = __shfl(sidx, j);
        const int s1 = __shfl(sidx, j + 1);
        const int s2 = __shfl(sidx, j + 2);
        const int s3 = __shfl(sidx, j + 3);
        acc0 += Y[(size_t)s0 * 64 + lane];
        acc1 += Y[(size_t)s1 * 64 + lane];
        acc2 += Y[(size_t)s2 * 64 + lane];
        acc3 += Y[(size_t)s3 * 64 + lane];
      }
      for (; j < m; ++j) {
        const int s0 = __shfl(sidx, j);
        acc0 += Y[(size_t)s0 * 64 + lane];
      }
    }
    const float inv = 1.0f / fmaxf((float)(e1 - e0), 1.0f);
    const float h =
        fmaxf(fmaf((acc0 + acc1) + (acc2 + acc3), inv, bl + zv), 0.0f);
    H[(size_t)row * 64 + lane] = h;
    if (FINAL) {
      float p0 = h * wh0, p1 = h * wh1, p2 = h * wh2, p3 = h * wh3, p4 = h * wh4;
      for (int o = 32; o > 0; o >>= 1) {
        p0 += __shfl_xor(p0, o);
        p1 += __shfl_xor(p1, o);
        p2 += __shfl_xor(p2, o);
        p3 += __shfl_xor(p3, o);
        p4 += __shfl_xor(p4, o);
      }
      if (lane == 0) {
        logits[(size_t)row * 5 + 0] = p0 + bh[0];
        logits[(size_t)row * 5 + 1] = p1 + bh[1];
        logits[(size_t)row * 5 + 2] = p2 + bh[2];
        logits[(size_t)row * 5 + 3] = p3 + bh[3];
        logits[(size_t)row * 5 + 4] = p4 + bh[4];
      }
    }
  }
}

extern "C" void kernel_launch(void* const* d_in, const int* in_sizes, int n_in,
                              void* d_out, int out_size, void* d_ws, size_t ws_size,
                              hipStream_t stream) {
  const float* x = (const float*)d_in[0];
  const int* edge = (const int*)d_in[1];
  const float* W1l = (const float*)d_in[2];
  const float* b1l = (const float*)d_in[3];
  const float* W1r = (const float*)d_in[4];
  const float* W2l = (const float*)d_in[5];
  const float* b2l = (const float*)d_in[6];
  const float* W2r = (const float*)d_in[7];
  const float* Wh = (const float*)d_in[8];
  const float* bh = (const float*)d_in[9];
  const int* src = edge;
  const int* dst = edge + N_EDGES;

  float* out = (float*)d_out;
  float* logits = out;                            // [N,5]
  float* hout = out + (size_t)N_NODES * OUT_DIM;  // [N,64]

  const size_t N64 = (size_t)N_NODES * 64;
  float* y = (float*)d_ws;        // [N,64]
  float* z = y + N64;             // [N,64]
  float* h1 = z + N64;            // [N,64]
  int* bcount = (int*)(h1 + N64);   // [NBUCK]
  int* boff = bcount + NBUCK;       // [NBUCK+1]
  int* bcursor = boff + NBUCK + 1;  // [NBUCK]
  int* bedge = bcursor + NBUCK;     // [E]
  int* csr = bedge + N_EDGES;       // [E]
  int* noff = csr + N_EDGES;        // [N+1]

  // ---- CSR build via bucket sort (once; shared by both layers) ----
  hipMemsetAsync(bcount, 0, NBUCK * sizeof(int), stream);
  hipMemsetAsync(bcursor, 0, NBUCK * sizeof(int), stream);
  bcount_k<<<512, 256, 0, stream>>>(dst, bcount, N_EDGES);
  bscan_k<<<1, 256, 0, stream>>>(bcount, boff, noff);
  fillB_k<<<NBLK_FILL, 256, 0, stream>>>(src, dst, boff, bcursor, bedge);
  csrfill_k<<<NBUCK, 256, 0, stream>>>(boff, bedge, csr, noff);

  const int gblocks = (N_NODES + 63) / 64;
  const int wblocks = (N_NODES * 64 + 255) / 256;  // one wave per row

  // ---- layer 1 ----
  gemm_dual<IN_DIM><<<gblocks, 256, 0, stream>>>(x, W1l, W1r, y, z, N_NODES);
  gather_k<false><<<wblocks, 256, 0, stream>>>(noff, csr, y, z, b1l, nullptr,
                                               nullptr, h1, nullptr, N_NODES);

  // ---- layer 2 + head ----
  gemm_dual<HID><<<gblocks, 256, 0, stream>>>(h1, W2l, W2r, y, z, N_NODES);
  gather_k<true><<<wblocks, 256, 0, stream>>>(noff, csr, y, z, b2l, Wh, bh, hout,
                                              logits, N_NODES);
}

// Round 5
// 311.957 us; speedup vs baseline: 10.2771x; 1.8311x over previous
//
#include <hip/hip_runtime.h>

#define N_NODES 100000
#define IN_DIM 128
#define HID 64
#define OUT_DIM 5
#define N_EDGES 3200000

#define BSHIFT 7
#define BROWS 128  // nodes per bucket
#define NBUCK ((N_NODES + BROWS - 1) / BROWS)  // 782
#define FILL_CHUNK 16384
#define NBLK_FILL ((N_EDGES + FILL_CHUNK - 1) / FILL_CHUNK)  // 196

typedef __attribute__((ext_vector_type(8))) short short8;
typedef __attribute__((ext_vector_type(4))) float f32x4;
typedef unsigned short ushort_t;
typedef unsigned int uint_t;

static __device__ inline ushort_t f2bf(float f) {
  union { float f; uint_t u; } v; v.f = f;
  const uint_t r = v.u + 0x7FFFu + ((v.u >> 16) & 1u);  // RNE
  return (ushort_t)(r >> 16);
}
static __device__ inline uint_t pack2(float a, float b) {
  return (uint_t)f2bf(a) | ((uint_t)f2bf(b) << 16);
}

// ---- bucket histogram: bcount[dst>>7] += 1, LDS-aggregated ----
__global__ __launch_bounds__(256) void bcount_k(const int* __restrict__ dst,
                                                int* __restrict__ bcount, int E) {
  __shared__ int h[NBUCK];
  const int t = threadIdx.x;
  for (int i = t; i < NBUCK; i += 256) h[i] = 0;
  __syncthreads();
  int i = blockIdx.x * blockDim.x + t;
  const int stride = gridDim.x * blockDim.x;
  for (int e = i; e < E; e += stride) atomicAdd(&h[dst[e] >> BSHIFT], 1);
  __syncthreads();
  for (int b = t; b < NBUCK; b += 256) {
    const int v = h[b];
    if (v) atomicAdd(&bcount[b], v);
  }
}

// ---- exclusive scan of 782 bucket counts (single block); also noff sentinel ----
__global__ __launch_bounds__(256) void bscan_k(const int* __restrict__ bcount,
                                               int* __restrict__ boff,
                                               int* __restrict__ noff) {
  __shared__ int tsum[256];
  const int t = threadIdx.x;
  int v[4];
  int s = 0;
#pragma unroll
  for (int j = 0; j < 4; ++j) {
    const int idx = t * 4 + j;
    v[j] = (idx < NBUCK) ? bcount[idx] : 0;
    s += v[j];
  }
  tsum[t] = s;
  __syncthreads();
  for (int off = 1; off < 256; off <<= 1) {
    int x = (t >= off) ? tsum[t - off] : 0;
    __syncthreads();
    tsum[t] += x;
    __syncthreads();
  }
  int pre = tsum[t] - s;
#pragma unroll
  for (int j = 0; j < 4; ++j) {
    const int idx = t * 4 + j;
    if (idx < NBUCK) boff[idx] = pre;
    pre += v[j];
  }
  if (t == 0) {
    boff[NBUCK] = N_EDGES;
    noff[N_NODES] = N_EDGES;
  }
}

// ---- two-level bucket fill: per-block LDS histogram + range reservation ----
__global__ __launch_bounds__(256) void fillB_k(const int* __restrict__ src,
                                               const int* __restrict__ dst,
                                               const int* __restrict__ boff,
                                               int* __restrict__ bcursor,
                                               int* __restrict__ bedge) {
  __shared__ int hist[NBUCK];
  __shared__ int base[NBUCK];
  __shared__ int cur[NBUCK];
  const int t = threadIdx.x;
  const int e0 = blockIdx.x * FILL_CHUNK;
  const int e1 = min(e0 + FILL_CHUNK, N_EDGES);
  for (int i = t; i < NBUCK; i += 256) {
    hist[i] = 0;
    cur[i] = 0;
  }
  __syncthreads();
  for (int e = e0 + t; e < e1; e += 256) atomicAdd(&hist[dst[e] >> BSHIFT], 1);
  __syncthreads();
  for (int b = t; b < NBUCK; b += 256) {
    const int v = hist[b];
    base[b] = v ? atomicAdd(&bcursor[b], v) : 0;
  }
  __syncthreads();
  for (int e = e0 + t; e < e1; e += 256) {
    const int d = dst[e];
    const int b = d >> BSHIFT;
    const int pos = boff[b] + base[b] + atomicAdd(&cur[b], 1);
    bedge[pos] = (src[e] << BSHIFT) | (d & (BROWS - 1));
  }
}

// ---- bucket -> full CSR: block per bucket, LDS counting sort ----
__global__ __launch_bounds__(256) void csrfill_k(const int* __restrict__ boff,
                                                 const int* __restrict__ bedge,
                                                 int* __restrict__ csr,
                                                 int* __restrict__ noff) {
  __shared__ int hist[BROWS];
  __shared__ int sc[BROWS];
  __shared__ int cur[BROWS];
  const int t = threadIdx.x;
  const int b = blockIdx.x;
  const int e0 = boff[b];
  const int e1 = boff[b + 1];
  if (t < BROWS) {
    hist[t] = 0;
    cur[t] = 0;
  }
  __syncthreads();
  for (int e = e0 + t; e < e1; e += 256) atomicAdd(&hist[bedge[e] & (BROWS - 1)], 1);
  __syncthreads();
  if (t < BROWS) sc[t] = hist[t];
  __syncthreads();
  for (int off = 1; off < BROWS; off <<= 1) {
    int x = (t >= off && t < BROWS) ? sc[t - off] : 0;
    __syncthreads();
    if (t < BROWS) sc[t] += x;
    __syncthreads();
  }
  if (t < BROWS) {
    const int node = b * BROWS + t;
    if (node < N_NODES) noff[node] = e0 + sc[t] - hist[t];
    sc[t] -= hist[t];
  }
  __syncthreads();
  for (int e = e0 + t; e < e1; e += 256) {
    const int p = bedge[e];
    const int d = p & (BROWS - 1);
    const int pos = e0 + sc[d] + atomicAdd(&cur[d], 1);
    csr[pos] = p >> BSHIFT;
  }
}

// ---- MFMA dual GEMM: Yb = bf16(X @ Wl^T), Z = X @ Wr^T  (W: [64][K] row-major) ----
// Block: 256 thr / 4 waves; tile 128 rows x 64 cols; bf16 LDS with XOR swizzle.
template <int K>
__global__ __launch_bounds__(256) void gemm_mfma(const float* __restrict__ X,
                                                 const float* __restrict__ Wl,
                                                 const float* __restrict__ Wr,
                                                 ushort_t* __restrict__ Yb,
                                                 float* __restrict__ Z, int n) {
  __shared__ uint4 ldsq[(256 * K * 2) / 16];  // 128 X-rows + 2*64 W-rows, bf16
  char* xlds = (char*)ldsq;
  char* wlds = xlds + 128 * K * 2;
  const int t = threadIdx.x;
  const int lane = t & 63;
  const int wv = t >> 6;
  const int rowBase = blockIdx.x * 128;
  const int K2 = K * 2;
  const int KC = K / 8;  // 16B chunks per row

  // stage X (f32 -> bf16, swizzled)
  for (int c = t; c < 128 * KC; c += 256) {
    const int r = c / KC, k8 = c - r * KC;
    const int row = rowBase + r;
    uint4 w = {0u, 0u, 0u, 0u};
    if (row < n) {
      const float4* p = (const float4*)(X + (size_t)row * K + k8 * 8);
      const float4 f0 = p[0];
      const float4 f1 = p[1];
      w.x = pack2(f0.x, f0.y);
      w.y = pack2(f0.z, f0.w);
      w.z = pack2(f1.x, f1.y);
      w.w = pack2(f1.z, f1.w);
    }
    const int byte = (r * K2 + k8 * 16) ^ ((r & 7) << 4);
    *(uint4*)(xlds + byte) = w;
  }
  // stage Wl, Wr
  for (int c = t; c < 2 * 64 * KC; c += 256) {
    const int m = c / (64 * KC);
    const int c2 = c - m * 64 * KC;
    const int r = c2 / KC, k8 = c2 - r * KC;
    const float4* p = (const float4*)((m ? Wr : Wl) + (size_t)r * K + k8 * 8);
    const float4 f0 = p[0];
    const float4 f1 = p[1];
    uint4 w;
    w.x = pack2(f0.x, f0.y);
    w.y = pack2(f0.z, f0.w);
    w.z = pack2(f1.x, f1.y);
    w.w = pack2(f1.z, f1.w);
    const int byte = (m * 64 * K2) + ((r * K2 + k8 * 16) ^ ((r & 7) << 4));
    *(uint4*)(wlds + byte) = w;
  }
  __syncthreads();

  f32x4 accY[2][4], accZ[2][4];
#pragma unroll
  for (int rt = 0; rt < 2; ++rt)
#pragma unroll
    for (int ct = 0; ct < 4; ++ct) {
      accY[rt][ct] = (f32x4){0.f, 0.f, 0.f, 0.f};
      accZ[rt][ct] = (f32x4){0.f, 0.f, 0.f, 0.f};
    }

  const int fr = lane & 15;
  const int kg = lane >> 4;
#pragma unroll
  for (int kk = 0; kk < K / 32; ++kk) {
    const int kbyte = kk * 64 + kg * 16;
    short8 a[2];
#pragma unroll
    for (int rt = 0; rt < 2; ++rt) {
      const int r = wv * 32 + rt * 16 + fr;
      a[rt] = *(const short8*)(xlds + ((r * K2 + kbyte) ^ ((r & 7) << 4)));
    }
#pragma unroll
    for (int ct = 0; ct < 4; ++ct) {
      const int wr = ct * 16 + fr;
      const int byteY = (wr * K2 + kbyte) ^ ((wr & 7) << 4);
      const short8 bY = *(const short8*)(wlds + byteY);
      const short8 bZ = *(const short8*)(wlds + byteY + 64 * K2);
#pragma unroll
      for (int rt = 0; rt < 2; ++rt) {
        accY[rt][ct] =
            __builtin_amdgcn_mfma_f32_16x16x32_bf16(a[rt], bY, accY[rt][ct], 0, 0, 0);
        accZ[rt][ct] =
            __builtin_amdgcn_mfma_f32_16x16x32_bf16(a[rt], bZ, accZ[rt][ct], 0, 0, 0);
      }
    }
  }

  // epilogue: D row=(lane>>4)*4+q, col=lane&15  [m89-verified]
#pragma unroll
  for (int rt = 0; rt < 2; ++rt) {
#pragma unroll
    for (int q = 0; q < 4; ++q) {
      const int row = rowBase + wv * 32 + rt * 16 + kg * 4 + q;
      if (row < n) {
#pragma unroll
        for (int ct = 0; ct < 4; ++ct) {
          const int col = ct * 16 + fr;
          Yb[(size_t)row * 64 + col] = f2bf(accY[rt][ct][q]);
          Z[(size_t)row * 64 + col] = accZ[rt][ct][q];
        }
      }
    }
  }
}

// ---- gather-reduce per node (bf16 Y) + fused epilogue ----
template <bool FINAL>
__global__ __launch_bounds__(256) void gather_k(
    const int* __restrict__ noff, const int* __restrict__ csr,
    const ushort_t* __restrict__ Yb, const float* __restrict__ Z,
    const float* __restrict__ bias, const float* __restrict__ Wh,
    const float* __restrict__ bh, float* __restrict__ H,
    float* __restrict__ logits, int n) {
  const int lane = threadIdx.x & 63;
  const int wid = (blockIdx.x * blockDim.x + threadIdx.x) >> 6;
  const int nw = (gridDim.x * blockDim.x) >> 6;
  float wh0 = 0.f, wh1 = 0.f, wh2 = 0.f, wh3 = 0.f, wh4 = 0.f;
  if (FINAL) {
    wh0 = Wh[0 * 64 + lane];
    wh1 = Wh[1 * 64 + lane];
    wh2 = Wh[2 * 64 + lane];
    wh3 = Wh[3 * 64 + lane];
    wh4 = Wh[4 * 64 + lane];
  }
  const float bl = bias[lane];

  for (int row = wid; row < n; row += nw) {
    const int e0 = noff[row];
    const int e1 = noff[row + 1];
    const float zv = Z[(size_t)row * 64 + lane];
    float acc0 = 0.0f, acc1 = 0.0f, acc2 = 0.0f, acc3 = 0.0f;
    for (int eb = e0; eb < e1; eb += 64) {
      const int m = min(64, e1 - eb);
      const int sidx = (eb + lane < e1) ? csr[eb + lane] : 0;
      int j = 0;
      for (; j + 3 < m; j += 4) {
        const int s0 = __shfl(sidx, j);
        const int s1 = __shfl(sidx, j + 1);
        const int s2 = __shfl(sidx, j + 2);
        const int s3 = __shfl(sidx, j + 3);
        acc0 += __uint_as_float((uint_t)Yb[(size_t)s0 * 64 + lane] << 16);
        acc1 += __uint_as_float((uint_t)Yb[(size_t)s1 * 64 + lane] << 16);
        acc2 += __uint_as_float((uint_t)Yb[(size_t)s2 * 64 + lane] << 16);
        acc3 += __uint_as_float((uint_t)Yb[(size_t)s3 * 64 + lane] << 16);
      }
      for (; j < m; ++j) {
        const int s0 = __shfl(sidx, j);
        acc0 += __uint_as_float((uint_t)Yb[(size_t)s0 * 64 + lane] << 16);
      }
    }
    const float inv = 1.0f / fmaxf((float)(e1 - e0), 1.0f);
    const float h = fmaxf(fmaf((acc0 + acc1) + (acc2 + acc3), inv, bl + zv), 0.0f);
    H[(size_t)row * 64 + lane] = h;
    if (FINAL) {
      float p0 = h * wh0, p1 = h * wh1, p2 = h * wh2, p3 = h * wh3, p4 = h * wh4;
      for (int o = 32; o > 0; o >>= 1) {
        p0 += __shfl_xor(p0, o);
        p1 += __shfl_xor(p1, o);
        p2 += __shfl_xor(p2, o);
        p3 += __shfl_xor(p3, o);
        p4 += __shfl_xor(p4, o);
      }
      if (lane == 0) {
        logits[(size_t)row * 5 + 0] = p0 + bh[0];
        logits[(size_t)row * 5 + 1] = p1 + bh[1];
        logits[(size_t)row * 5 + 2] = p2 + bh[2];
        logits[(size_t)row * 5 + 3] = p3 + bh[3];
        logits[(size_t)row * 5 + 4] = p4 + bh[4];
      }
    }
  }
}

extern "C" void kernel_launch(void* const* d_in, const int* in_sizes, int n_in,
                              void* d_out, int out_size, void* d_ws, size_t ws_size,
                              hipStream_t stream) {
  const float* x = (const float*)d_in[0];
  const int* edge = (const int*)d_in[1];
  const float* W1l = (const float*)d_in[2];
  const float* b1l = (const float*)d_in[3];
  const float* W1r = (const float*)d_in[4];
  const float* W2l = (const float*)d_in[5];
  const float* b2l = (const float*)d_in[6];
  const float* W2r = (const float*)d_in[7];
  const float* Wh = (const float*)d_in[8];
  const float* bh = (const float*)d_in[9];
  const int* src = edge;
  const int* dst = edge + N_EDGES;

  float* out = (float*)d_out;
  float* logits = out;                            // [N,5]
  float* hout = out + (size_t)N_NODES * OUT_DIM;  // [N,64]

  const size_t N64 = (size_t)N_NODES * 64;
  float* z = (float*)d_ws;              // [N,64] f32
  float* h1 = z + N64;                  // [N,64] f32
  ushort_t* yb = (ushort_t*)(h1 + N64);  // [N,64] bf16
  int* bcount = (int*)(yb + N64);       // [NBUCK]
  int* boff = bcount + NBUCK;           // [NBUCK+1]
  int* bcursor = boff + NBUCK + 1;      // [NBUCK]
  int* bedge = bcursor + NBUCK;         // [E]
  int* csr = bedge + N_EDGES;           // [E]
  int* noff = csr + N_EDGES;            // [N+1]

  // ---- CSR build via bucket sort (once; shared by both layers) ----
  hipMemsetAsync(bcount, 0, NBUCK * sizeof(int), stream);
  hipMemsetAsync(bcursor, 0, NBUCK * sizeof(int), stream);
  bcount_k<<<512, 256, 0, stream>>>(dst, bcount, N_EDGES);
  bscan_k<<<1, 256, 0, stream>>>(bcount, boff, noff);
  fillB_k<<<NBLK_FILL, 256, 0, stream>>>(src, dst, boff, bcursor, bedge);
  csrfill_k<<<NBUCK, 256, 0, stream>>>(boff, bedge, csr, noff);

  const int mblocks = (N_NODES + 127) / 128;       // 782
  const int wblocks = (N_NODES * 64 + 255) / 256;  // one wave per row

  // ---- layer 1 ----
  gemm_mfma<IN_DIM><<<mblocks, 256, 0, stream>>>(x, W1l, W1r, yb, z, N_NODES);
  gather_k<false><<<wblocks, 256, 0, stream>>>(noff, csr, yb, z, b1l, nullptr,
                                               nullptr, h1, nullptr, N_NODES);

  // ---- layer 2 + head ----
  gemm_mfma<HID><<<mblocks, 256, 0, stream>>>(h1, W2l, W2r, yb, z, N_NODES);
  gather_k<true><<<wblocks, 256, 0, stream>>>(noff, csr, yb, z, b2l, Wh, bh, hout,
                                              logits, N_NODES);
}